// Round 10
// baseline (54.665 us; speedup 1.0000x reference)
//
#include <hip/hip_runtime.h>
#include <hip/hip_bf16.h>

#define SEQ 2048
#define HID 2048
#define NB  8
#define WMAX 30
#define SLAB 16
#define EPSF 1e-8f
#define NSEG ((size_t)NB * SEQ)

// ws layout (floats): [0] dot1 | [1] dot2 | [2] nsq | [3] slog | [4] endv(uint)

__device__ __forceinline__ float dot4(float4 a, float4 b) {
    return a.x * b.x + a.y * b.y + a.z * b.z + a.w * b.w;
}

// ---------------- Kernel 1: per-row dot1, dot2, nsq (+endv sentinel) ----------------
__global__ __launch_bounds__(512)
void k1_dots(const float* __restrict__ seq, const int* __restrict__ idxs,
             float* __restrict__ ws) {
    __shared__ float4 q1s[HID / 4];
    __shared__ float4 q2s[HID / 4];

    int bid = blockIdx.x;
    int b = bid >> 7;                 // 128 blocks per example
    int rbase = (bid & 127) * SLAB;
    int t = threadIdx.x;

    int sep0 = idxs[2 * b], sep1 = idxs[2 * b + 1];

    bool needed = (rbase == 0) || (rbase + SLAB > sep0 - 1 && rbase < sep1);
    if (!needed) return;

    const float4* q1p = (const float4*)(seq + ((size_t)b * SEQ + 1) * HID);
    const float4* q2p = (const float4*)(seq + ((size_t)b * SEQ + (sep0 - 1)) * HID);
    q1s[t] = q1p[t];
    q2s[t] = q2p[t];
    __syncthreads();

    int w = t >> 6, lane = t & 63;
    int iA = rbase + w;
    int iB = iA + 8;
    const float4* rpA = (const float4*)(seq + ((size_t)b * SEQ + iA) * HID);
    const float4* rpB = (const float4*)(seq + ((size_t)b * SEQ + iB) * HID);

    float a1 = 0.f, a2 = 0.f, a3 = 0.f;
    float c1 = 0.f, c2 = 0.f, c3 = 0.f;
#pragma unroll
    for (int k = 0; k < 8; ++k) {
        float4 vA = rpA[k * 64 + lane];
        float4 vB = rpB[k * 64 + lane];
        float4 x  = q1s[k * 64 + lane];
        float4 y  = q2s[k * 64 + lane];
        a1 += dot4(vA, x); a2 += dot4(vA, y); a3 += dot4(vA, vA);
        c1 += dot4(vB, x); c2 += dot4(vB, y); c3 += dot4(vB, vB);
    }
#pragma unroll
    for (int off = 32; off; off >>= 1) {
        a1 += __shfl_xor(a1, off);
        a2 += __shfl_xor(a2, off);
        a3 += __shfl_xor(a3, off);
        c1 += __shfl_xor(c1, off);
        c2 += __shfl_xor(c2, off);
        c3 += __shfl_xor(c3, off);
    }
    if (lane == 0) {
        size_t oA = (size_t)b * SEQ + iA;
        size_t oB = (size_t)b * SEQ + iB;
        unsigned* endv = (unsigned*)(ws + 4 * NSEG);
        ws[oA] = a1;
        ws[NSEG + oA] = a2;
        ws[2 * NSEG + oA] = a3;
        endv[oA] = 0u;
        ws[oB] = c1;
        ws[NSEG + oB] = c2;
        ws[2 * NSEG + oB] = c3;
        endv[oB] = 0u;
    }
}

// order-preserving uint encoding of float (no NaNs present).
__device__ __forceinline__ unsigned enc_f(float f) {
    unsigned u = __float_as_uint(f);
    return (u & 0x80000000u) ? ~u : (u | 0x80000000u);
}
__device__ __forceinline__ float dec_f(unsigned k) {
    unsigned u = (k & 0x80000000u) ? (k ^ 0x80000000u) : ~k;
    return __uint_as_float(u);
}

// ---------------- Kernel 2a: banded argmax + global scatter-max ----------------
// Idempotent: rewrites identical slog values; endv atomicMax re-applies the
// same maxima. Launched 3x this round for attribution.
__global__ __launch_bounds__(256)
void k2a_band(const float* __restrict__ ws, const int* __restrict__ idxs) {
    __shared__ float2 s2[256 + 32];

    int blk = blockIdx.x;
    int b = blk >> 3;
    int base = (blk & 7) * 256;
    int t = threadIdx.x;

    int sep0 = idxs[2 * b], sep1 = idxs[2 * b + 1];
    if (base >= sep1 || base + 256 <= sep0 + 1) return;

    const float* dot1 = ws + (size_t)b * SEQ;
    const float* dot2 = ws + NSEG + (size_t)b * SEQ;
    const float* nsq  = ws + 2 * NSEG + (size_t)b * SEQ;
    float* slog       = (float*)(ws + 3 * NSEG) + (size_t)b * SEQ;
    unsigned* endv    = (unsigned*)(ws + 4 * NSEG) + (size_t)b * SEQ;

    int g0 = base + t;
    s2[t] = make_float2(dot2[g0], nsq[g0]);
    if (t < 32) {
        int g1 = base + 256 + t;
        int gc = g1 > SEQ - 1 ? SEQ - 1 : g1;
        s2[256 + t] = make_float2(dot2[gc], nsq[gc]);
    }
    __syncthreads();

    float invq = 1.0f / fmaxf(sqrtf(nsq[1] + nsq[sep0 - 1]), EPSF);

    int i = base + t;
    bool range_ok = (i >= sep0 + 1) && (i < sep1);
    float d1 = dot1[i];
    float ni = s2[t].y;

    float best = -__builtin_inff();
    int arg = 0;
#pragma unroll
    for (int d = 0; d < WMAX; ++d) {
        int jraw = i + d;
        if (range_ok && jraw < sep1) {
            float2 v = s2[t + d];
            float sim = (d1 + v.x) * rsqrtf(ni + v.y) * invq;
            if (sim > best) { best = sim; arg = d; }
        }
    }
    if (range_ok) {
        slog[i] = best;
        int e = i + arg;
        atomicMax(&endv[e], enc_f(best));
    }
}

// ---------------- Kernel 2b: stats + flip + output ----------------
__global__ __launch_bounds__(1024)
void k2b_fin(const float* __restrict__ ws, const int* __restrict__ idxs,
             float* __restrict__ out) {
    __shared__ float red[5][16];

    int b = blockIdx.x;
    int t = threadIdx.x;
    int sep0 = idxs[2 * b], sep1 = idxs[2 * b + 1];

    const float* slogp = (const float*)(ws + 3 * NSEG) + (size_t)b * SEQ;
    const unsigned* ev = (const unsigned*)(ws + 4 * NSEG) + (size_t)b * SEQ;

    float slog[2], elog[2];
#pragma unroll
    for (int r = 0; r < 2; ++r) {
        int i = t + r * 1024;
        bool in_range = (i >= sep0 + 1) && (i < sep1);
        slog[r] = in_range ? slogp[i] : 0.0f;
        unsigned k = in_range ? ev[i] : 0u;
        elog[r] = (k == 0u) ? 0.0f : dec_f(k);
    }

    float ssum = 0.f, ssq = 0.f, esum = 0.f, esq = 0.f, smax = -__builtin_inff();
#pragma unroll
    for (int r = 0; r < 2; ++r) {
        ssum += slog[r]; ssq += slog[r] * slog[r];
        esum += elog[r]; esq += elog[r] * elog[r];
        smax = fmaxf(smax, slog[r]);
    }
#pragma unroll
    for (int off = 32; off; off >>= 1) {
        ssum += __shfl_xor(ssum, off);
        ssq  += __shfl_xor(ssq,  off);
        esum += __shfl_xor(esum, off);
        esq  += __shfl_xor(esq,  off);
        smax = fmaxf(smax, __shfl_xor(smax, off));
    }
    int lane = t & 63, w = t >> 6;
    if (lane == 0) {
        red[0][w] = ssum; red[1][w] = ssq; red[2][w] = esum;
        red[3][w] = esq;  red[4][w] = smax;
    }
    __syncthreads();

    float S0 = 0.f, S1 = 0.f, E0 = 0.f, E1 = 0.f, MX = -__builtin_inff();
#pragma unroll
    for (int k = 0; k < 16; ++k) {
        S0 += red[0][k]; S1 += red[1][k]; E0 += red[2][k];
        E1 += red[3][k]; MX = fmaxf(MX, red[4][k]);
    }
    float ms = S0 / SEQ;
    float ss = sqrtf(fmaxf(S1 - SEQ * ms * ms, 0.f) / (SEQ - 1));
    float me = E0 / SEQ;
    float se = sqrtf(fmaxf(E1 - SEQ * me * me, 0.f) / (SEQ - 1));
    bool flip = (MX < ms + ss) || (MX < me + se);

#pragma unroll
    for (int r = 0; r < 2; ++r) {
        int i = t + r * 1024;
        float so = slog[r], eo = elog[r];
        if (flip) {
            so = (so == 0.f) ? -0.001f : -so;
            eo = (eo == 0.f) ? -0.001f : -eo;
        }
        out[(size_t)b * SEQ + i] = so;
        out[NSEG + (size_t)b * SEQ + i] = eo;
    }
}

extern "C" void kernel_launch(void* const* d_in, const int* in_sizes, int n_in,
                              void* d_out, int out_size, void* d_ws, size_t ws_size,
                              hipStream_t stream) {
    const float* seq = (const float*)d_in[0];
    const int* idxs = (const int*)d_in[1];
    float* out = (float*)d_out;
    float* ws = (float*)d_ws;

    // ATTRIBUTION: k2a and k2b launched 3x each (idempotent).
    // dur = base + 2*[m(k2a) + m(k2b)].
    k1_dots<<<NB * 128, 512, 0, stream>>>(seq, idxs, ws);
    k2a_band<<<NB * 8, 256, 0, stream>>>(ws, idxs);
    k2a_band<<<NB * 8, 256, 0, stream>>>(ws, idxs);
    k2a_band<<<NB * 8, 256, 0, stream>>>(ws, idxs);
    k2b_fin<<<NB, 1024, 0, stream>>>(ws, idxs, out);
    k2b_fin<<<NB, 1024, 0, stream>>>(ws, idxs, out);
    k2b_fin<<<NB, 1024, 0, stream>>>(ws, idxs, out);
}

// Round 11
// 33.260 us; speedup vs baseline: 1.6436x; 1.6436x over previous
//
#include <hip/hip_runtime.h>
#include <hip/hip_bf16.h>

#define SEQ 2048
#define HID 2048
#define NB  8
#define WMAX 30
#define SLAB 16
#define EPSF 1e-8f
#define ENC_NEGINF 0x007fffffu
#define NSEG ((size_t)NB * SEQ)

// ws layout (floats): [0] dot1 | [1] dot2 | [2] nsq  (each NB*SEQ)

__device__ __forceinline__ float dot4(float4 a, float4 b) {
    return a.x * b.x + a.y * b.y + a.z * b.z + a.w * b.w;
}

// ---------------- Kernel 1: per-row dot1, dot2, nsq ----------------
// 512 threads = 8 waves, 2 rows per wave -> 16 rows/block. Grid = NB*128.
// Only rows {1} U [sep0-1, sep1) are consumed downstream; blocks fully
// outside exit before issuing row loads (~28% byte cut). k1 exec is at the
// achievable HBM ceiling (~97 MB @ ~6.3 TB/s, measured via 3x-launch
// attribution in R7).
__global__ __launch_bounds__(512)
void k1_dots(const float* __restrict__ seq, const int* __restrict__ idxs,
             float* __restrict__ ws) {
    __shared__ float4 q1s[HID / 4];
    __shared__ float4 q2s[HID / 4];

    int bid = blockIdx.x;
    int b = bid >> 7;                 // 128 blocks per example
    int rbase = (bid & 127) * SLAB;
    int t = threadIdx.x;

    int sep0 = idxs[2 * b], sep1 = idxs[2 * b + 1];

    bool needed = (rbase == 0) || (rbase + SLAB > sep0 - 1 && rbase < sep1);
    if (!needed) return;

    const float4* q1p = (const float4*)(seq + ((size_t)b * SEQ + 1) * HID);
    const float4* q2p = (const float4*)(seq + ((size_t)b * SEQ + (sep0 - 1)) * HID);
    q1s[t] = q1p[t];
    q2s[t] = q2p[t];
    __syncthreads();

    int w = t >> 6, lane = t & 63;
    int iA = rbase + w;
    int iB = iA + 8;
    const float4* rpA = (const float4*)(seq + ((size_t)b * SEQ + iA) * HID);
    const float4* rpB = (const float4*)(seq + ((size_t)b * SEQ + iB) * HID);

    float a1 = 0.f, a2 = 0.f, a3 = 0.f;
    float c1 = 0.f, c2 = 0.f, c3 = 0.f;
#pragma unroll
    for (int k = 0; k < 8; ++k) {
        float4 vA = rpA[k * 64 + lane];
        float4 vB = rpB[k * 64 + lane];
        float4 x  = q1s[k * 64 + lane];
        float4 y  = q2s[k * 64 + lane];
        a1 += dot4(vA, x); a2 += dot4(vA, y); a3 += dot4(vA, vA);
        c1 += dot4(vB, x); c2 += dot4(vB, y); c3 += dot4(vB, vB);
    }
#pragma unroll
    for (int off = 32; off; off >>= 1) {
        a1 += __shfl_xor(a1, off);
        a2 += __shfl_xor(a2, off);
        a3 += __shfl_xor(a3, off);
        c1 += __shfl_xor(c1, off);
        c2 += __shfl_xor(c2, off);
        c3 += __shfl_xor(c3, off);
    }
    if (lane == 0) {
        size_t oA = (size_t)b * SEQ + iA;
        size_t oB = (size_t)b * SEQ + iB;
        ws[oA] = a1;
        ws[NSEG + oA] = a2;
        ws[2 * NSEG + oA] = a3;
        ws[oB] = c1;
        ws[NSEG + oB] = c2;
        ws[2 * NSEG + oB] = c3;
    }
}

// order-preserving uint encoding of float (no NaNs present)
__device__ __forceinline__ unsigned enc_f(float f) {
    unsigned u = __float_as_uint(f);
    return (u & 0x80000000u) ? ~u : (u | 0x80000000u);
}
__device__ __forceinline__ float dec_f(unsigned k) {
    unsigned u = (k & 0x80000000u) ? (k ^ 0x80000000u) : ~k;
    return __uint_as_float(u);
}

// ---------------- Kernel 2: band + scatter-max + stats + flip + out ----------------
// One block per example, 1024 threads, 2 rows/thread. Everything in LDS.
// (dot2,nsq) packed as float2 -> one ds_read_b64 per band tap. Only rows in
// [sep0+1, sep1) are consumed from ws (skipped k1 rows are never decoded:
// band taps stay within [i, i+29] subset of computed rows; evs is
// LDS-initialized here).
__global__ __launch_bounds__(1024)
void k2_all(const float* __restrict__ ws, const int* __restrict__ idxs,
            float* __restrict__ out) {
    __shared__ float2 s2[SEQ];        // (dot2, nsq)
    __shared__ unsigned evs[SEQ];
    __shared__ float red[5][16];

    int b = blockIdx.x;
    int t = threadIdx.x;
    int sep0 = idxs[2 * b], sep1 = idxs[2 * b + 1];

    const float* dot1 = ws + (size_t)b * SEQ;
    const float* dot2 = ws + NSEG + (size_t)b * SEQ;
    const float* nsq  = ws + 2 * NSEG + (size_t)b * SEQ;

#pragma unroll
    for (int r = 0; r < 2; ++r) {
        int ii = t + r * 1024;
        s2[ii] = make_float2(dot2[ii], nsq[ii]);
        evs[ii] = ENC_NEGINF;
    }
    __syncthreads();

    float invq = 1.0f / fmaxf(sqrtf(s2[1].y + s2[sep0 - 1].y), EPSF);

    float slog[2];
#pragma unroll
    for (int r = 0; r < 2; ++r) {
        int ii = t + r * 1024;
        bool range_ok = (ii >= sep0 + 1) && (ii < sep1);
        float d1 = dot1[ii];
        float ni = s2[ii].y;
        float best = -__builtin_inff();
        int arg = 0;
#pragma unroll
        for (int d = 0; d < WMAX; ++d) {
            int jraw = ii + d;
            if (range_ok && jraw < sep1) {   // valid => jraw <= 2045, in-bounds
                float2 v = s2[jraw];
                float sim = (d1 + v.x) * rsqrtf(ni + v.y) * invq;
                if (sim > best) { best = sim; arg = d; }
            }
        }
        slog[r] = range_ok ? best : 0.0f;    // any == range_ok (d=0 always valid)
        if (range_ok) {
            int e = ii + arg;
            if (e > SEQ - 1) e = SEQ - 1;
            atomicMax(&evs[e], enc_f(best));
        }
    }
    __syncthreads();

    float elog[2];
#pragma unroll
    for (int r = 0; r < 2; ++r) {
        int ii = t + r * 1024;
        unsigned k = evs[ii];
        elog[r] = (k == ENC_NEGINF) ? 0.0f : dec_f(k);
    }

    float ssum = 0.f, ssq = 0.f, esum = 0.f, esq = 0.f, smax = -__builtin_inff();
#pragma unroll
    for (int r = 0; r < 2; ++r) {
        ssum += slog[r]; ssq += slog[r] * slog[r];
        esum += elog[r]; esq += elog[r] * elog[r];
        smax = fmaxf(smax, slog[r]);
    }
#pragma unroll
    for (int off = 32; off; off >>= 1) {
        ssum += __shfl_xor(ssum, off);
        ssq  += __shfl_xor(ssq,  off);
        esum += __shfl_xor(esum, off);
        esq  += __shfl_xor(esq,  off);
        smax = fmaxf(smax, __shfl_xor(smax, off));
    }
    int lane = t & 63, w = t >> 6;
    if (lane == 0) {
        red[0][w] = ssum; red[1][w] = ssq; red[2][w] = esum;
        red[3][w] = esq;  red[4][w] = smax;
    }
    __syncthreads();

    float S0 = 0.f, S1 = 0.f, E0 = 0.f, E1 = 0.f, MX = -__builtin_inff();
#pragma unroll
    for (int k = 0; k < 16; ++k) {
        S0 += red[0][k]; S1 += red[1][k]; E0 += red[2][k];
        E1 += red[3][k]; MX = fmaxf(MX, red[4][k]);
    }
    float ms = S0 / SEQ;
    float ss = sqrtf(fmaxf(S1 - SEQ * ms * ms, 0.f) / (SEQ - 1));
    float me = E0 / SEQ;
    float se = sqrtf(fmaxf(E1 - SEQ * me * me, 0.f) / (SEQ - 1));
    bool flip = (MX < ms + ss) || (MX < me + se);

#pragma unroll
    for (int r = 0; r < 2; ++r) {
        int ii = t + r * 1024;
        float so = slog[r], eo = elog[r];
        if (flip) {
            so = (so == 0.f) ? -0.001f : -so;
            eo = (eo == 0.f) ? -0.001f : -eo;
        }
        out[(size_t)b * SEQ + ii] = so;
        out[NSEG + (size_t)b * SEQ + ii] = eo;
    }
}

extern "C" void kernel_launch(void* const* d_in, const int* in_sizes, int n_in,
                              void* d_out, int out_size, void* d_ws, size_t ws_size,
                              hipStream_t stream) {
    const float* seq = (const float*)d_in[0];
    const int* idxs = (const int*)d_in[1];
    float* out = (float*)d_out;
    float* ws = (float*)d_ws;

    k1_dots<<<NB * 128, 512, 0, stream>>>(seq, idxs, ws);
    k2_all<<<NB, 1024, 0, stream>>>(ws, idxs, out);
}